// Round 4
// baseline (915.059 us; speedup 1.0000x reference)
//
#include <hip/hip_runtime.h>

#define B_SZ     32
#define IN_DIM   1024
#define K_TOTAL  525824          // 1024 linear + 524800 triu
#define OUT_DIM  512
#define BK       256
#define NCHUNK   2054            // K_TOTAL / BK exactly
#define KGROUPS  8
#define OGROUPS  32              // 16 outputs per block
#define NEED_WS  ((size_t)B_SZ * K_TOTAL * sizeof(float))   // 67.3 MB

// ---------------------------------------------------------------- bias init
__global__ void bias_init_kernel(const float* __restrict__ bias, float* __restrict__ out)
{
    int i = blockIdx.x * 256 + threadIdx.x;     // 16384 total
    out[i] = bias[i & (OUT_DIM - 1)];
}

// ------------------------------------------------- kernel A: feature expand
// Block r (0..1023): quad row r -> f[b][1024+off(r)+j] = x[b][r]*x[b][r+j]
// Block 1024: linear part f[b][k] = x[b][k]
__global__ __launch_bounds__(256)
void feat_kernel(const float* __restrict__ x, float* __restrict__ f)
{
    const int r   = blockIdx.x;
    const int tid = threadIdx.x;

    if (r == IN_DIM) {
        for (int b = 0; b < B_SZ; ++b)
            for (int k = tid; k < IN_DIM; k += 256)
                f[(size_t)b * K_TOTAL + k] = x[b * IN_DIM + k];
        return;
    }

    const int len = IN_DIM - r;
    const size_t base = (size_t)IN_DIM + (size_t)r * IN_DIM - (((size_t)r * (r - 1)) >> 1);
    for (int b = 0; b < B_SZ; ++b) {
        const float  xr   = x[b * IN_DIM + r];
        const float* xrow = x + b * IN_DIM + r;
        float*       frow = f + (size_t)b * K_TOTAL + base;
        for (int j = tid; j < len; j += 256)
            frow[j] = xr * xrow[j];
    }
}

// ------------------------------------------- kernel B: pipelined tall GEMM
// out[b][o] += sum_k W[o][k] * f[b][k]; block tile 16 o x 32 b, BK=256/chunk.
__global__ __launch_bounds__(512, 2)
void qgemm_ws_kernel(const float* __restrict__ f,
                     const float* __restrict__ W,
                     float* __restrict__ out)
{
    __shared__ float ft[2][B_SZ][BK];           // 2 x 32 KB double buffer

    const int tid  = threadIdx.x;
    const int lane = tid & 63;
    const int wave = tid >> 6;                  // 0..7
    const int bgrp = wave & 3;                  // 8 batches each
    const int ogrp = wave >> 2;                 // 8 outputs each

    const int og = blockIdx.x & (OGROUPS - 1);  // 0..31
    const int kg = blockIdx.x / OGROUPS;        // 0..7

    const int o_base = og * 16 + ogrp * 8;
    const int b_base = bgrp * 8;

    float acc[8][8];
    #pragma unroll
    for (int i = 0; i < 8; ++i)
        #pragma unroll
        for (int o = 0; o < 8; ++o) acc[i][o] = 0.f;

    float4 fr[4];                               // staged f (next chunk)
    float4 wv_n[8];                             // W prefetch (next chunk)

    int c = kg;
    // ---- prologue: stage f(c) into buf0, prefetch W(c)
    #pragma unroll
    for (int i = 0; i < 4; ++i) {
        const int q = tid + i * 512;            // 0..2047 float4 slots
        fr[i] = *(const float4*)(f + (size_t)(q >> 6) * K_TOTAL
                                   + (size_t)c * BK + ((q & 63) << 2));
    }
    #pragma unroll
    for (int o = 0; o < 8; ++o)
        wv_n[o] = *(const float4*)(W + (size_t)(o_base + o) * K_TOTAL
                                     + (size_t)c * BK + (lane << 2));
    #pragma unroll
    for (int i = 0; i < 4; ++i) {
        const int q = tid + i * 512;
        *(float4*)&ft[0][q >> 6][(q & 63) << 2] = fr[i];
    }
    __syncthreads();

    int cur = 0;
    for (; c < NCHUNK; c += KGROUPS) {
        const int  cn   = c + KGROUPS;
        const bool next = (cn < NCHUNK);

        float4 wv_c[8];
        #pragma unroll
        for (int o = 0; o < 8; ++o) wv_c[o] = wv_n[o];

        if (next) {
            #pragma unroll
            for (int i = 0; i < 4; ++i) {
                const int q = tid + i * 512;
                fr[i] = *(const float4*)(f + (size_t)(q >> 6) * K_TOTAL
                                           + (size_t)cn * BK + ((q & 63) << 2));
            }
            #pragma unroll
            for (int o = 0; o < 8; ++o)
                wv_n[o] = *(const float4*)(W + (size_t)(o_base + o) * K_TOTAL
                                             + (size_t)cn * BK + (lane << 2));
        }

        // ---- compute current chunk from LDS (no outstanding-load waits)
        #pragma unroll
        for (int i = 0; i < 8; ++i) {
            const float4 xv = *(const float4*)&ft[cur][b_base + i][lane << 2];
            #pragma unroll
            for (int o = 0; o < 8; ++o)
                acc[i][o] += xv.x * wv_c[o].x + xv.y * wv_c[o].y
                           + xv.z * wv_c[o].z + xv.w * wv_c[o].w;
        }

        if (next) {
            #pragma unroll
            for (int i = 0; i < 4; ++i) {
                const int q = tid + i * 512;
                *(float4*)&ft[cur ^ 1][q >> 6][(q & 63) << 2] = fr[i];
            }
        }
        __syncthreads();
        cur ^= 1;
    }

    // ---- wave butterfly over k-lanes, then one atomic per element
    #pragma unroll
    for (int i = 0; i < 8; ++i)
        #pragma unroll
        for (int o = 0; o < 8; ++o) {
            float v = acc[i][o];
            #pragma unroll
            for (int m = 1; m < 64; m <<= 1)
                v += __shfl_xor(v, m);
            acc[i][o] = v;
        }

    if (lane == 0) {
        #pragma unroll
        for (int i = 0; i < 8; ++i)
            #pragma unroll
            for (int o = 0; o < 8; ++o)
                atomicAdd(&out[(b_base + i) * OUT_DIM + o_base + o], acc[i][o]);
    }
}

// ------------------------------------------------- fallback (v2, no ws use)
__global__ __launch_bounds__(512, 2)
void qgemm_fallback_kernel(const float* __restrict__ x,
                           const float* __restrict__ W,
                           float* __restrict__ out)
{
    __shared__ float xt[B_SZ][512];

    const int tid  = threadIdx.x;
    const int lane = tid & 63;
    const int wave = tid >> 6;
    const int bgrp = wave & 3;
    const int ogrp = wave >> 2;

    const int og = blockIdx.x & 31;
    const int kg = blockIdx.x >> 5;             // 0..15

    const int o_base = og * 16 + ogrp * 8;
    const int b_base = bgrp * 8;

    float acc[8][8];
    #pragma unroll
    for (int i = 0; i < 8; ++i)
        #pragma unroll
        for (int o = 0; o < 8; ++o) acc[i][o] = 0.f;

    const int nch = (K_TOTAL + 511) / 512;      // 1027
    for (int chunk = kg; chunk < nch; chunk += 16) {
        const int k = chunk * 512 + tid;
        __syncthreads();
        if (k < IN_DIM) {
            #pragma unroll
            for (int b = 0; b < B_SZ; ++b)
                xt[b][tid] = x[b * IN_DIM + k];
        } else {
            const int t = k - IN_DIM;
            double disc = 4198401.0 - 8.0 * (double)t;
            int r = (int)((2049.0 - sqrt(disc)) * 0.5);
            int off = r * IN_DIM - ((r * (r - 1)) >> 1);
            if (t < off) { --r; off = r * IN_DIM - ((r * (r - 1)) >> 1); }
            else if (t >= off + (IN_DIM - r)) { off += IN_DIM - r; ++r; }
            const int ccol = r + (t - off);
            #pragma unroll
            for (int b = 0; b < B_SZ; ++b)
                xt[b][tid] = x[b * IN_DIM + r] * x[b * IN_DIM + ccol];
        }
        __syncthreads();

        const float* wrow = W + (size_t)o_base * K_TOTAL + (size_t)chunk * 512;
        #pragma unroll
        for (int pass = 0; pass < 2; ++pass) {
            const int kk = pass * 256 + lane * 4;
            float4 wv[8];
            #pragma unroll
            for (int o = 0; o < 8; ++o)
                wv[o] = *(const float4*)(wrow + (size_t)o * K_TOTAL + kk);
            float4 xv[8];
            #pragma unroll
            for (int i = 0; i < 8; ++i)
                xv[i] = *(const float4*)&xt[b_base + i][kk];
            #pragma unroll
            for (int o = 0; o < 8; ++o)
                #pragma unroll
                for (int i = 0; i < 8; ++i)
                    acc[i][o] += xv[i].x * wv[o].x + xv[i].y * wv[o].y
                               + xv[i].z * wv[o].z + xv[i].w * wv[o].w;
        }
    }

    #pragma unroll
    for (int i = 0; i < 8; ++i)
        #pragma unroll
        for (int o = 0; o < 8; ++o) {
            float v = acc[i][o];
            #pragma unroll
            for (int m = 1; m < 64; m <<= 1)
                v += __shfl_xor(v, m);
            acc[i][o] = v;
        }

    if (lane == 0) {
        #pragma unroll
        for (int i = 0; i < 8; ++i)
            #pragma unroll
            for (int o = 0; o < 8; ++o)
                atomicAdd(&out[(b_base + i) * OUT_DIM + o_base + o], acc[i][o]);
    }
}

extern "C" void kernel_launch(void* const* d_in, const int* in_sizes, int n_in,
                              void* d_out, int out_size, void* d_ws, size_t ws_size,
                              hipStream_t stream)
{
    const float* x    = (const float*)d_in[0];   // [32,1024] fp32
    const float* W    = (const float*)d_in[1];   // [512, 525824] fp32
    const float* bias = (const float*)d_in[2];   // [512] fp32
    float* out = (float*)d_out;                  // [32,512] fp32

    hipLaunchKernelGGL(bias_init_kernel, dim3(64), dim3(256), 0, stream, bias, out);

    if (ws_size >= NEED_WS) {
        float* f = (float*)d_ws;
        hipLaunchKernelGGL(feat_kernel, dim3(IN_DIM + 1), dim3(256), 0, stream, x, f);
        hipLaunchKernelGGL(qgemm_ws_kernel, dim3(OGROUPS * KGROUPS), dim3(512), 0, stream,
                           f, W, out);
    } else {
        hipLaunchKernelGGL(qgemm_fallback_kernel, dim3(512), dim3(512), 0, stream,
                           x, W, out);
    }
}

// Round 5
// 521.674 us; speedup vs baseline: 1.7541x; 1.7541x over previous
//
#include <hip/hip_runtime.h>

#define B_SZ     32
#define IN_DIM   1024
#define K_TOTAL  525824          // 1024 linear + 524800 triu
#define OUT_DIM  512
#define BK       256
#define NCHUNK   2054            // K_TOTAL / BK exactly
#define KG       8
#define OG       32              // 16 outputs per block
#define NEED_WS  ((size_t)B_SZ * K_TOTAL * sizeof(float))   // 67.3 MB

// async global->LDS, 16B per lane; LDS dest = wave-uniform base + lane*16
#define GLD16(g, l) __builtin_amdgcn_global_load_lds(                      \
    (const __attribute__((address_space(1))) void*)(g),                    \
    (__attribute__((address_space(3))) void*)(l), 16, 0, 0)

// ---------------------------------------------------------------- bias init
__global__ void bias_init_kernel(const float* __restrict__ bias, float* __restrict__ out)
{
    int i = blockIdx.x * 256 + threadIdx.x;     // 16384 total
    out[i] = bias[i & (OUT_DIM - 1)];
}

// ------------------------------------------------- kernel A: feature expand
__global__ __launch_bounds__(256)
void feat_kernel(const float* __restrict__ x, float* __restrict__ f)
{
    const int r   = blockIdx.x;
    const int tid = threadIdx.x;

    if (r == IN_DIM) {
        for (int b = 0; b < B_SZ; ++b)
            for (int k = tid; k < IN_DIM; k += 256)
                f[(size_t)b * K_TOTAL + k] = x[b * IN_DIM + k];
        return;
    }

    const int len = IN_DIM - r;
    const size_t base = (size_t)IN_DIM + (size_t)r * IN_DIM - (((size_t)r * (r - 1)) >> 1);
    for (int b = 0; b < B_SZ; ++b) {
        const float  xr   = x[b * IN_DIM + r];
        const float* xrow = x + b * IN_DIM + r;
        float*       frow = f + (size_t)b * K_TOTAL + base;
        for (int j = tid; j < len; j += 256)
            frow[j] = xr * xrow[j];
    }
}

// ---------------- kernel B: 2-phase global_load_lds double-buffered GEMM
// block: 16 outputs x 32 batches, 8 waves (2 og' x 4 bg), lanes span k.
__global__ __launch_bounds__(512, 2)
void qgemm_kernel(const float* __restrict__ f,
                  const float* __restrict__ W,
                  float* __restrict__ out)
{
    __shared__ float fbuf[2][B_SZ][BK];          // 64 KB
    __shared__ float wbuf[2][16][BK];            // 32 KB

    const int tid  = threadIdx.x;
    const int lane = tid & 63;
    const int wv_  = tid >> 6;                   // wave 0..7
    const int ogrp = wv_ >> 2;                   // 0..1
    const int bgrp = wv_ & 3;                    // 0..3

    const int og = blockIdx.x >> 3;              // 0..31
    const int kg = blockIdx.x & 7;               // 0..7 (same-kg blocks share f in one XCD L2)

    const int o_block = og * 16;
    const int o_w     = ogrp * 8;
    const int b_base  = bgrp * 8;
    const int col     = lane << 2;               // float index within chunk

    float acc[8][8];
    #pragma unroll
    for (int i = 0; i < 8; ++i)
        #pragma unroll
        for (int o = 0; o < 8; ++o) acc[i][o] = 0.f;

    // stage chunk c into buffer s: zero VGPRs live afterwards
    #define STAGE(s, c)                                                          \
    do {                                                                         \
        const size_t kof = (size_t)(c) * BK + col;                               \
        _Pragma("unroll")                                                        \
        for (int j = 0; j < 4; ++j) {                                            \
            const int row = wv_ + j * 8;         /* 0..31 */                     \
            GLD16(f + (size_t)row * K_TOTAL + kof, &fbuf[s][row][0]);            \
        }                                                                        \
        _Pragma("unroll")                                                        \
        for (int j = 0; j < 2; ++j) {                                            \
            const int row = wv_ + j * 8;         /* 0..15 */                     \
            GLD16(W + (size_t)(o_block + row) * K_TOTAL + kof, &wbuf[s][row][0]);\
        }                                                                        \
    } while (0)

    STAGE(0, kg);
    __syncthreads();                             // drains vmcnt(0) + barrier

    int cur = 0;
    for (int c = kg; c < NCHUNK; c += KG) {
        const int cn = c + KG;
        if (cn < NCHUNK) STAGE(cur ^ 1, cn);     // async into other buffer

        float4 wvv[8];
        #pragma unroll
        for (int o = 0; o < 8; ++o)
            wvv[o] = *(const float4*)&wbuf[cur][o_w + o][col];
        float4 fvv[8];
        #pragma unroll
        for (int i = 0; i < 8; ++i)
            fvv[i] = *(const float4*)&fbuf[cur][b_base + i][col];

        #pragma unroll
        for (int i = 0; i < 8; ++i)
            #pragma unroll
            for (int o = 0; o < 8; ++o)
                acc[i][o] += fvv[i].x * wvv[o].x + fvv[i].y * wvv[o].y
                           + fvv[i].z * wvv[o].z + fvv[i].w * wvv[o].w;

        __syncthreads();                         // staged loads landed; readers done
        cur ^= 1;
    }
    #undef STAGE

    // butterfly-reduce each acc element over the 64 k-lanes
    #pragma unroll
    for (int i = 0; i < 8; ++i)
        #pragma unroll
        for (int o = 0; o < 8; ++o) {
            float v = acc[i][o];
            #pragma unroll
            for (int m = 1; m < 64; m <<= 1)
                v += __shfl_xor(v, m);
            acc[i][o] = v;
        }

    if (lane == 0) {
        #pragma unroll
        for (int i = 0; i < 8; ++i)
            #pragma unroll
            for (int o = 0; o < 8; ++o)
                atomicAdd(&out[(b_base + i) * OUT_DIM + o_block + o_w + o], acc[i][o]);
    }
}

// ------------------------------------------------- fallback (proven v2 path)
__global__ __launch_bounds__(512, 2)
void qgemm_fallback_kernel(const float* __restrict__ x,
                           const float* __restrict__ W,
                           float* __restrict__ out)
{
    __shared__ float xt[B_SZ][512];

    const int tid  = threadIdx.x;
    const int lane = tid & 63;
    const int wave = tid >> 6;
    const int bgrp = wave & 3;
    const int ogrp = wave >> 2;

    const int og = blockIdx.x & 31;
    const int kgf = blockIdx.x >> 5;

    const int o_base = og * 16 + ogrp * 8;
    const int b_base = bgrp * 8;

    float acc[8][8];
    #pragma unroll
    for (int i = 0; i < 8; ++i)
        #pragma unroll
        for (int o = 0; o < 8; ++o) acc[i][o] = 0.f;

    const int nch = (K_TOTAL + 511) / 512;
    for (int chunk = kgf; chunk < nch; chunk += 16) {
        const int k = chunk * 512 + tid;
        __syncthreads();
        if (k < IN_DIM) {
            #pragma unroll
            for (int b = 0; b < B_SZ; ++b)
                xt[b][tid] = x[b * IN_DIM + k];
        } else {
            const int t = k - IN_DIM;
            double disc = 4198401.0 - 8.0 * (double)t;
            int r = (int)((2049.0 - sqrt(disc)) * 0.5);
            int off = r * IN_DIM - ((r * (r - 1)) >> 1);
            if (t < off) { --r; off = r * IN_DIM - ((r * (r - 1)) >> 1); }
            else if (t >= off + (IN_DIM - r)) { off += IN_DIM - r; ++r; }
            const int ccol = r + (t - off);
            #pragma unroll
            for (int b = 0; b < B_SZ; ++b)
                xt[b][tid] = x[b * IN_DIM + r] * x[b * IN_DIM + ccol];
        }
        __syncthreads();

        const float* wrow = W + (size_t)o_base * K_TOTAL + (size_t)chunk * 512;
        #pragma unroll
        for (int pass = 0; pass < 2; ++pass) {
            const int kk = pass * 256 + lane * 4;
            float4 wv[8];
            #pragma unroll
            for (int o = 0; o < 8; ++o)
                wv[o] = *(const float4*)(wrow + (size_t)o * K_TOTAL + kk);
            float4 xv[8];
            #pragma unroll
            for (int i = 0; i < 8; ++i)
                xv[i] = *(const float4*)&xt[b_base + i][kk];
            #pragma unroll
            for (int o = 0; o < 8; ++o)
                #pragma unroll
                for (int i = 0; i < 8; ++i)
                    acc[i][o] += xv[i].x * wv[o].x + xv[i].y * wv[o].y
                               + xv[i].z * wv[o].z + xv[i].w * wv[o].w;
        }
    }

    #pragma unroll
    for (int i = 0; i < 8; ++i)
        #pragma unroll
        for (int o = 0; o < 8; ++o) {
            float v = acc[i][o];
            #pragma unroll
            for (int m = 1; m < 64; m <<= 1)
                v += __shfl_xor(v, m);
            acc[i][o] = v;
        }

    if (lane == 0) {
        #pragma unroll
        for (int i = 0; i < 8; ++i)
            #pragma unroll
            for (int o = 0; o < 8; ++o)
                atomicAdd(&out[(b_base + i) * OUT_DIM + o_base + o], acc[i][o]);
    }
}

extern "C" void kernel_launch(void* const* d_in, const int* in_sizes, int n_in,
                              void* d_out, int out_size, void* d_ws, size_t ws_size,
                              hipStream_t stream)
{
    const float* x    = (const float*)d_in[0];   // [32,1024] fp32
    const float* W    = (const float*)d_in[1];   // [512, 525824] fp32
    const float* bias = (const float*)d_in[2];   // [512] fp32
    float* out = (float*)d_out;                  // [32,512] fp32

    hipLaunchKernelGGL(bias_init_kernel, dim3(64), dim3(256), 0, stream, bias, out);

    if (ws_size >= NEED_WS) {
        float* f = (float*)d_ws;
        hipLaunchKernelGGL(feat_kernel, dim3(IN_DIM + 1), dim3(256), 0, stream, x, f);
        hipLaunchKernelGGL(qgemm_kernel, dim3(OG * KG), dim3(512), 0, stream,
                           f, W, out);
    } else {
        hipLaunchKernelGGL(qgemm_fallback_kernel, dim3(512), dim3(512), 0, stream,
                           x, W, out);
    }
}

// Round 6
// 505.618 us; speedup vs baseline: 1.8098x; 1.0318x over previous
//
#include <hip/hip_runtime.h>

#define B_SZ     32
#define IN_DIM   1024
#define K_TOTAL  525824          // 1024 linear + 524800 triu
#define OUT_DIM  512
#define BK       256
#define NCHUNK   2054            // K_TOTAL / BK exactly
#define KG       8
#define NEED_WS  ((size_t)B_SZ * K_TOTAL * sizeof(float))   // 67.3 MB

// async global->LDS, 16B per lane; LDS dest = wave-uniform base + lane*16
#define GLD16(g, l) __builtin_amdgcn_global_load_lds(                      \
    (const __attribute__((address_space(1))) void*)(g),                    \
    (__attribute__((address_space(3))) void*)(l), 16, 0, 0)

// ---------------------------------------------------------------- bias init
__global__ void bias_init_kernel(const float* __restrict__ bias, float* __restrict__ out)
{
    int i = blockIdx.x * 256 + threadIdx.x;     // 16384 total
    out[i] = bias[i & (OUT_DIM - 1)];
}

// ------------------------------------------------- kernel A: feature expand
__global__ __launch_bounds__(256)
void feat_kernel(const float* __restrict__ x, float* __restrict__ f)
{
    const int r   = blockIdx.x;
    const int tid = threadIdx.x;

    if (r == IN_DIM) {
        for (int b = 0; b < B_SZ; ++b)
            for (int k = tid; k < IN_DIM; k += 256)
                f[(size_t)b * K_TOTAL + k] = x[b * IN_DIM + k];
        return;
    }

    const int len = IN_DIM - r;
    const size_t base = (size_t)IN_DIM + (size_t)r * IN_DIM - (((size_t)r * (r - 1)) >> 1);
    for (int b = 0; b < B_SZ; ++b) {
        const float  xr   = x[b * IN_DIM + r];
        const float* xrow = x + b * IN_DIM + r;
        float*       frow = f + (size_t)b * K_TOTAL + base;
        for (int j = tid; j < len; j += 256)
            frow[j] = xr * xrow[j];
    }
}

// --------- kernel B: f via global_load_lds (32 KB LDS), W reg-dbuf, 2 blk/CU
// block tile 16b x 16o; 8 waves = 2 bgrp(8b) x 4 ogrp(4o); lanes span k.
__global__ __launch_bounds__(512, 4)            // cap 128 VGPR -> 2 blocks/CU
void qgemm_kernel(const float* __restrict__ f,
                  const float* __restrict__ W,
                  float* __restrict__ out)
{
    __shared__ float fbuf[2][16][BK];            // 32 KB double buffer

    const int tid  = threadIdx.x;
    const int lane = tid & 63;
    const int wv_  = tid >> 6;                   // wave 0..7
    const int bgrp = wv_ & 1;                    // 8 batches each
    const int ogrp = wv_ >> 1;                   // 0..3, 4 outputs each

    const int og = blockIdx.x >> 4;              // 0..31
    const int bg = (blockIdx.x >> 3) & 1;        // 0..1  (pair differs by 8 -> same XCD)
    const int kg = blockIdx.x & 7;               // 0..7  (f-sharing blocks co-XCD)

    const int o_base = og * 16 + ogrp * 4;
    const int b_loc  = bgrp * 8;                 // fbuf row base
    const int b_glob = bg * 16 + b_loc;          // global batch base
    const int col    = lane << 2;                // float index in chunk

    const float* wrow = W + (size_t)o_base * K_TOTAL;
    const float* frow = f + (size_t)(bg * 16) * K_TOTAL;

    float acc[8][4];
    #pragma unroll
    for (int i = 0; i < 8; ++i)
        #pragma unroll
        for (int j = 0; j < 4; ++j) acc[i][j] = 0.f;

    // stage 16 f-rows of chunk c into buffer s (2 wave-loads per wave)
    #define STAGE(s, c)                                                         \
    do {                                                                        \
        const size_t kof = (size_t)(c) * BK + col;                              \
        _Pragma("unroll")                                                       \
        for (int j = 0; j < 2; ++j) {                                           \
            const int row = wv_ + j * 8;         /* 0..15 */                    \
            GLD16(frow + (size_t)row * K_TOTAL + kof, &fbuf[s][row][0]);        \
        }                                                                       \
    } while (0)

    #define WLOAD(dst, c)                                                       \
    do {                                                                        \
        const size_t kof = (size_t)(c) * BK + col;                              \
        _Pragma("unroll")                                                       \
        for (int j = 0; j < 4; ++j)                                             \
            dst[j] = *(const float4*)(wrow + (size_t)j * K_TOTAL + kof);        \
    } while (0)

    float4 wv_n[4];
    STAGE(0, kg);
    WLOAD(wv_n, kg);
    __syncthreads();

    int cur = 0;
    for (int c = kg; c < NCHUNK; c += KG) {
        const int  cn   = c + KG;
        const bool next = (cn < NCHUNK);

        float4 wv_c[4];
        #pragma unroll
        for (int j = 0; j < 4; ++j) wv_c[j] = wv_n[j];

        if (next) {                               // issue-early (T14): hide under compute
            STAGE(cur ^ 1, cn);
            WLOAD(wv_n, cn);
        }

        #pragma unroll
        for (int i = 0; i < 8; ++i) {
            const float4 fv = *(const float4*)&fbuf[cur][b_loc + i][col];
            #pragma unroll
            for (int j = 0; j < 4; ++j)
                acc[i][j] += fv.x * wv_c[j].x + fv.y * wv_c[j].y
                           + fv.z * wv_c[j].z + fv.w * wv_c[j].w;
        }

        __syncthreads();                          // staged f landed; readers done
        cur ^= 1;
    }
    #undef STAGE
    #undef WLOAD

    // butterfly-reduce each acc element over the 64 k-lanes
    #pragma unroll
    for (int i = 0; i < 8; ++i)
        #pragma unroll
        for (int j = 0; j < 4; ++j) {
            float v = acc[i][j];
            #pragma unroll
            for (int m = 1; m < 64; m <<= 1)
                v += __shfl_xor(v, m);
            acc[i][j] = v;
        }

    if (lane == 0) {
        #pragma unroll
        for (int i = 0; i < 8; ++i)
            #pragma unroll
            for (int j = 0; j < 4; ++j)
                atomicAdd(&out[(b_glob + i) * OUT_DIM + o_base + j], acc[i][j]);
    }
}

// ------------------------------------------------- fallback (proven v2 path)
__global__ __launch_bounds__(512, 2)
void qgemm_fallback_kernel(const float* __restrict__ x,
                           const float* __restrict__ W,
                           float* __restrict__ out)
{
    __shared__ float xt[B_SZ][512];

    const int tid  = threadIdx.x;
    const int lane = tid & 63;
    const int wave = tid >> 6;
    const int bgrp = wave & 3;
    const int ogrp = wave >> 2;

    const int og  = blockIdx.x & 31;
    const int kgf = blockIdx.x >> 5;

    const int o_base = og * 16 + ogrp * 8;
    const int b_base = bgrp * 8;

    float acc[8][8];
    #pragma unroll
    for (int i = 0; i < 8; ++i)
        #pragma unroll
        for (int o = 0; o < 8; ++o) acc[i][o] = 0.f;

    const int nch = (K_TOTAL + 511) / 512;
    for (int chunk = kgf; chunk < nch; chunk += 16) {
        const int k = chunk * 512 + tid;
        __syncthreads();
        if (k < IN_DIM) {
            #pragma unroll
            for (int b = 0; b < B_SZ; ++b)
                xt[b][tid] = x[b * IN_DIM + k];
        } else {
            const int t = k - IN_DIM;
            double disc = 4198401.0 - 8.0 * (double)t;
            int r = (int)((2049.0 - sqrt(disc)) * 0.5);
            int off = r * IN_DIM - ((r * (r - 1)) >> 1);
            if (t < off) { --r; off = r * IN_DIM - ((r * (r - 1)) >> 1); }
            else if (t >= off + (IN_DIM - r)) { off += IN_DIM - r; ++r; }
            const int ccol = r + (t - off);
            #pragma unroll
            for (int b = 0; b < B_SZ; ++b)
                xt[b][tid] = x[b * IN_DIM + r] * x[b * IN_DIM + ccol];
        }
        __syncthreads();

        const float* wrow = W + (size_t)o_base * K_TOTAL + (size_t)chunk * 512;
        #pragma unroll
        for (int pass = 0; pass < 2; ++pass) {
            const int kk = pass * 256 + lane * 4;
            float4 wv[8];
            #pragma unroll
            for (int o = 0; o < 8; ++o)
                wv[o] = *(const float4*)(wrow + (size_t)o * K_TOTAL + kk);
            float4 xv[8];
            #pragma unroll
            for (int i = 0; i < 8; ++i)
                xv[i] = *(const float4*)&xt[b_base + i][kk];
            #pragma unroll
            for (int o = 0; o < 8; ++o)
                #pragma unroll
                for (int i = 0; i < 8; ++i)
                    acc[i][o] += xv[i].x * wv[o].x + xv[i].y * wv[o].y
                               + xv[i].z * wv[o].z + xv[i].w * wv[o].w;
        }
    }

    #pragma unroll
    for (int i = 0; i < 8; ++i)
        #pragma unroll
        for (int o = 0; o < 8; ++o) {
            float v = acc[i][o];
            #pragma unroll
            for (int m = 1; m < 64; m <<= 1)
                v += __shfl_xor(v, m);
            acc[i][o] = v;
        }

    if (lane == 0) {
        #pragma unroll
        for (int i = 0; i < 8; ++i)
            #pragma unroll
            for (int o = 0; o < 8; ++o)
                atomicAdd(&out[(b_base + i) * OUT_DIM + o_base + o], acc[i][o]);
    }
}

extern "C" void kernel_launch(void* const* d_in, const int* in_sizes, int n_in,
                              void* d_out, int out_size, void* d_ws, size_t ws_size,
                              hipStream_t stream)
{
    const float* x    = (const float*)d_in[0];   // [32,1024] fp32
    const float* W    = (const float*)d_in[1];   // [512, 525824] fp32
    const float* bias = (const float*)d_in[2];   // [512] fp32
    float* out = (float*)d_out;                  // [32,512] fp32

    hipLaunchKernelGGL(bias_init_kernel, dim3(64), dim3(256), 0, stream, bias, out);

    if (ws_size >= NEED_WS) {
        float* f = (float*)d_ws;
        hipLaunchKernelGGL(feat_kernel, dim3(IN_DIM + 1), dim3(256), 0, stream, x, f);
        hipLaunchKernelGGL(qgemm_kernel, dim3(512), dim3(512), 0, stream, f, W, out);
    } else {
        hipLaunchKernelGGL(qgemm_fallback_kernel, dim3(512), dim3(512), 0, stream,
                           x, W, out);
    }
}